// Round 7
// baseline (491.154 us; speedup 1.0000x reference)
//
#include <hip/hip_runtime.h>
#include <hip/hip_fp16.h>

// ---------------------------------------------------------------------------
// 2-layer GCN on MI355X.
// R1: 3-phase scan. R2: h fp16. R3: two-level LDS counting-sort CSR build.
// R5: fp16 MFMA GEMMs (mfma_f32_16x16x32_f16), W pre-transposed.
// R6: XCD-sliced aggregation. R5 profile showed FETCH=193MB = 8 XCD x 25.6MB
//     (each XCD's private L2 fetches all of h once — structural floor).
//     Fix: h stored in column-slab layout [C/16][N][16] fp16 (32B/node/slab);
//     agg blocks process one 16-col slice, slice = blockIdx%NSL; round-robin
//     block->XCD dispatch pins slice k to XCD k -> 3.2MB slab stays
//     L2-resident. ssrc re-streamed NSL times via nontemporal loads; out
//     written nontemporal. 16 edges in flight/wave (4 lanes x 8B per edge).
// R7: fix compile — nontemporal_store needs clang ext_vector (f32x4), not
//     HIP_vector_type float4.
// ---------------------------------------------------------------------------

typedef _Float16 half8 __attribute__((ext_vector_type(8)));
typedef float f32x4 __attribute__((ext_vector_type(4)));

constexpr int BK_SHIFT = 7;               // 128 nodes per bucket
constexpr int BK_NODES = 1 << BK_SHIFT;
constexpr int NB_MAX   = 1024;
constexpr int SLAB     = 2560;            // mean 2046 + 11 sigma
constexpr int P1_EPT   = 32;
constexpr int P1_EDGES = 256 * P1_EPT;    // 8192

// ---- pass 1: LDS counting sort of 8192 edges into coarse buckets ----
__global__ __launch_bounds__(256) void k_p1(const int* __restrict__ src,
                                            const int* __restrict__ dst, int E,
                                            int NB, int* __restrict__ bfill,
                                            unsigned* __restrict__ slab) {
  __shared__ unsigned stage[P1_EDGES];
  __shared__ unsigned short bidp[P1_EDGES];
  __shared__ int hist[NB_MAX];
  __shared__ int lbase[NB_MAX];
  __shared__ int goff[NB_MAX];
  __shared__ int part[256];

  const int t = threadIdx.x;
  const long base = (long)blockIdx.x * P1_EDGES;
  const int nval = (int)(((long)E - base < (long)P1_EDGES) ? (E - base) : P1_EDGES);

  for (int i = t; i < NB; i += 256) hist[i] = 0;
  __syncthreads();

  int eb[P1_EPT];
  unsigned ev[P1_EPT];
#pragma unroll
  for (int i = 0; i < P1_EPT; ++i) {
    long e = base + t + i * 256;
    int b = -1;
    unsigned v = 0;
    if (e < E) {
      int d = dst[e];
      int s = src[e];
      b = d >> BK_SHIFT;
      v = ((unsigned)(d & (BK_NODES - 1)) << 17) | (unsigned)s;
      atomicAdd(&hist[b], 1);
    }
    eb[i] = b;
    ev[i] = v;
  }
  __syncthreads();

  int lc[4];
  int lsum = 0;
#pragma unroll
  for (int j = 0; j < 4; ++j) {
    int b = t * 4 + j;
    lc[j] = (b < NB) ? hist[b] : 0;
    lsum += lc[j];
  }
  part[t] = lsum;
  __syncthreads();
  for (int o = 1; o < 256; o <<= 1) {
    int a = (t >= o) ? part[t - o] : 0;
    __syncthreads();
    part[t] += a;
    __syncthreads();
  }
  int run = part[t] - lsum;
#pragma unroll
  for (int j = 0; j < 4; ++j) {
    int b = t * 4 + j;
    if (b < NB) lbase[b] = run;
    run += lc[j];
  }
  __syncthreads();

  for (int b = t; b < NB; b += 256) {
    int len = hist[b];
    int g = len ? atomicAdd(&bfill[b], len) : 0;
    goff[b] = b * SLAB + g - lbase[b];
  }
  __syncthreads();

#pragma unroll
  for (int i = 0; i < P1_EPT; ++i) {
    if (eb[i] >= 0) {
      int p = atomicAdd(&lbase[eb[i]], 1);
      stage[p] = ev[i];
      bidp[p] = (unsigned short)eb[i];
    }
  }
  __syncthreads();

  for (int p = t; p < nval; p += 256) {
    int b = bidp[p];
    slab[goff[b] + p] = stage[p];
  }
}

__global__ __launch_bounds__(1024) void k_bscan(const int* __restrict__ bfill, int NB,
                                                int* __restrict__ bbase) {
  __shared__ int sm[1024];
  const int t = threadIdx.x;
  int v = (t < NB) ? bfill[t] : 0;
  sm[t] = v;
  __syncthreads();
  for (int o = 1; o < 1024; o <<= 1) {
    int a = (t >= o) ? sm[t - o] : 0;
    __syncthreads();
    sm[t] += a;
    __syncthreads();
  }
  if (t < NB) bbase[t] = sm[t] - v;
}

__global__ __launch_bounds__(256) void k_p2(const unsigned* __restrict__ slab,
                                            const int* __restrict__ bfill,
                                            const int* __restrict__ bbase, int N,
                                            int* __restrict__ deg,
                                            int* __restrict__ row_ptr,
                                            float* __restrict__ dinv,
                                            int* __restrict__ ssrc) {
  __shared__ int hist[BK_NODES];
  __shared__ int lb[BK_NODES];
  const int b = blockIdx.x;
  const int t = threadIdx.x;
  const int len = bfill[b];
  const int gbase = bbase[b];
  const unsigned* seg = slab + (size_t)b * SLAB;

  if (t < BK_NODES) hist[t] = 0;
  __syncthreads();
  for (int i = t; i < len; i += 256) atomicAdd(&hist[seg[i] >> 17], 1);
  __syncthreads();

  if (t < BK_NODES) lb[t] = hist[t];
  __syncthreads();
  for (int o = 1; o < BK_NODES; o <<= 1) {
    int a = 0;
    if (t < BK_NODES && t >= o) a = lb[t - o];
    __syncthreads();
    if (t < BK_NODES) lb[t] += a;
    __syncthreads();
  }

  int n = b * BK_NODES + t;
  if (t < BK_NODES && n < N) {
    int d = hist[t];
    deg[n] = d;
    row_ptr[n] = gbase + lb[t] - d;
    dinv[n] = rsqrtf((float)(d + 1));
  }
  __syncthreads();
  if (t < BK_NODES) lb[t] -= hist[t];
  __syncthreads();

  for (int i = t; i < len; i += 256) {
    unsigned v = seg[i];
    int l = v >> 17;
    int p = atomicAdd(&lb[l], 1);
    ssrc[gbase + p] = (int)(v & 0x1FFFF);
  }
}

// ---- prep: W (fp32, [K][NC]) -> Wt (fp16, [NC][K]) ----
__global__ __launch_bounds__(256) void k_prep(const float* __restrict__ W1,
                                              const float* __restrict__ W2,
                                              __half* __restrict__ Wt1,
                                              __half* __restrict__ Wt2) {
  int i = blockIdx.x * blockDim.x + threadIdx.x;
  if (i < 16384) {
    int k = i >> 7, n = i & 127;
    Wt1[n * 128 + k] = __float2half(W1[i]);
  } else if (i < 24576) {
    int j = i - 16384;
    int k = j >> 6, n = j & 63;
    Wt2[n * 128 + k] = __float2half(W2[j]);
  }
}

// ---- MFMA GEMM: H_slab[nt][row][lm] = (X @ W)[row][nt*16+lm] * dinv[row].
// Output in column-slab layout: slab nt (16 cols) contiguous [N][16] fp16.
template <int NC>
__global__ __launch_bounds__(256) void k_gemm(const float* __restrict__ X,
                                              const __half* __restrict__ Wt,
                                              const float* __restrict__ dinv,
                                              __half* __restrict__ Hs, int N) {
  constexpr int K = 128;
  constexpr int BM = 64;
  constexpr int LDK = K + 8;
  constexpr int NT = NC / 16;
  __shared__ _Float16 xs[BM * LDK];
  __shared__ _Float16 wl[NC * LDK];

  const int t = threadIdx.x;
  const int r0 = blockIdx.x * BM;

  for (int i = t; i < BM * (K / 4); i += 256) {
    int row = i >> 5, kg = i & 31;
    float4 v = make_float4(0.f, 0.f, 0.f, 0.f);
    if (r0 + row < N)
      v = *reinterpret_cast<const float4*>(X + (size_t)(r0 + row) * K + 4 * kg);
    union { _Float16 h[4]; unsigned long long u; } pk;
    pk.h[0] = (_Float16)v.x; pk.h[1] = (_Float16)v.y;
    pk.h[2] = (_Float16)v.z; pk.h[3] = (_Float16)v.w;
    *reinterpret_cast<unsigned long long*>(&xs[row * LDK + 4 * kg]) = pk.u;
  }
  for (int i = t; i < NC * (K / 8); i += 256) {
    int n = i >> 4, kc = i & 15;
    float4 raw = *reinterpret_cast<const float4*>(Wt + (size_t)n * K + 8 * kc);
    *reinterpret_cast<float4*>(&wl[n * LDK + 8 * kc]) = raw;
  }
  __syncthreads();

  const int w = t >> 6;
  const int lane = t & 63;
  const int lm = lane & 15;
  const int lg = lane >> 4;

  half8 a[4];
#pragma unroll
  for (int kt = 0; kt < 4; ++kt)
    a[kt] = *reinterpret_cast<const half8*>(&xs[(w * 16 + lm) * LDK + kt * 32 + lg * 8]);

  f32x4 acc[NT];
#pragma unroll
  for (int nt = 0; nt < NT; ++nt) acc[nt] = (f32x4){0.f, 0.f, 0.f, 0.f};

#pragma unroll
  for (int nt = 0; nt < NT; ++nt) {
#pragma unroll
    for (int kt = 0; kt < 4; ++kt) {
      half8 b = *reinterpret_cast<const half8*>(
          &wl[(nt * 16 + lm) * LDK + kt * 32 + lg * 8]);
      acc[nt] = __builtin_amdgcn_mfma_f32_16x16x32_f16(a[kt], b, acc[nt], 0, 0, 0);
    }
  }

  float dv[4];
#pragma unroll
  for (int r = 0; r < 4; ++r) {
    int row = r0 + w * 16 + lg * 4 + r;
    dv[r] = (row < N) ? dinv[row] : 0.f;
  }
#pragma unroll
  for (int nt = 0; nt < NT; ++nt) {
#pragma unroll
    for (int r = 0; r < 4; ++r) {
      int row = r0 + w * 16 + lg * 4 + r;
      if (row < N)
        Hs[(size_t)nt * N * 16 + (size_t)row * 16 + lm] =
            __float2half(acc[nt][r] * dv[r]);
    }
  }
}

// ---- XCD-sliced aggregation over one 16-col slice per block ----
// Hs: [C/16][N][16] fp16 slabs. slice = blockIdx % NSL -> pinned to one XCD
// by round-robin dispatch; slab (N*32B = 3.2MB) stays L2-resident.
// Wave: 16 edges in flight (eh = lane>>2), 4 lanes/edge x 8B; NPW nodes/wave.
template <int C, int NSL, bool RELU>
__global__ __launch_bounds__(256) void k_aggs(const __half* __restrict__ Hs,
                                              const int* __restrict__ rp,
                                              const int* __restrict__ dg,
                                              const int* __restrict__ ssrc,
                                              const float* __restrict__ dinv,
                                              const float* __restrict__ bias,
                                              float* __restrict__ out, int N) {
  constexpr int LOG = (NSL == 8) ? 3 : 2;
  constexpr int NPW = 8;
  const int wave = threadIdx.x >> 6;
  const int lane = threadIdx.x & 63;
  const int slice = blockIdx.x & (NSL - 1);
  const int g = blockIdx.x >> LOG;
  const int eh = lane >> 2;   // edge slot 0..15
  const int cl = lane & 3;    // 4-half chunk within the 16-col slice
  const __half* slabp = Hs + (size_t)slice * N * 16;
  const float4 bv = *reinterpret_cast<const float4*>(bias + slice * 16 + 4 * cl);

  const int n0 = (g * 4 + wave) * NPW;
  for (int ni = 0; ni < NPW; ++ni) {
    const int n = n0 + ni;
    if (n >= N) return;
    const int e0 = rp[n];
    const int e1 = e0 + dg[n];

    float acc[4] = {0.f, 0.f, 0.f, 0.f};
    auto gat = [&](int s) {
      uint2 raw = *reinterpret_cast<const uint2*>(slabp + (size_t)s * 16 + cl * 4);
      float2 fa = __half22float2(*reinterpret_cast<__half2*>(&raw.x));
      float2 fb = __half22float2(*reinterpret_cast<__half2*>(&raw.y));
      acc[0] += fa.x; acc[1] += fa.y; acc[2] += fb.x; acc[3] += fb.y;
    };
    if (eh == 0) gat(n);  // self loop
    int e = e0;
    for (; e + 16 <= e1; e += 16) {
      int s = __builtin_nontemporal_load(ssrc + e + eh);
      gat(s);
    }
    if (e + eh < e1) {
      int s = __builtin_nontemporal_load(ssrc + e + eh);
      gat(s);
    }

#pragma unroll
    for (int j = 0; j < 4; ++j) {
      acc[j] += __shfl_xor(acc[j], 4);
      acc[j] += __shfl_xor(acc[j], 8);
      acc[j] += __shfl_xor(acc[j], 16);
      acc[j] += __shfl_xor(acc[j], 32);
    }
    if (eh == 0) {
      const float dv = dinv[n];
      f32x4 o;
      o[0] = acc[0] * dv + bv.x;
      o[1] = acc[1] * dv + bv.y;
      o[2] = acc[2] * dv + bv.z;
      o[3] = acc[3] * dv + bv.w;
      if (RELU) {
        o[0] = fmaxf(o[0], 0.f); o[1] = fmaxf(o[1], 0.f);
        o[2] = fmaxf(o[2], 0.f); o[3] = fmaxf(o[3], 0.f);
      }
      __builtin_nontemporal_store(
          o, reinterpret_cast<f32x4*>(out + (size_t)n * C + slice * 16 + cl * 4));
    }
  }
}

extern "C" void kernel_launch(void* const* d_in, const int* in_sizes, int n_in,
                              void* d_out, int out_size, void* d_ws, size_t ws_size,
                              hipStream_t stream) {
  const float* x = (const float*)d_in[0];
  const int* ei = (const int*)d_in[1];
  const float* W1 = (const float*)d_in[2];
  const float* b1 = (const float*)d_in[3];
  const float* W2 = (const float*)d_in[4];
  const float* b2 = (const float*)d_in[5];

  const int K = 128;
  const int N = in_sizes[0] / K;     // 100000
  const int E = in_sizes[1] / 2;     // 1600000
  const int NB = (N + BK_NODES - 1) >> BK_SHIFT;  // 782
  if (NB > NB_MAX) return;

  const int* src = ei;
  const int* dst = ei + E;

  size_t off = 0;
  auto carve = [&](size_t bytes) {
    size_t o = off;
    off += (bytes + 255) & ~(size_t)255;
    return o;
  };
  char* ws = (char*)d_ws;
  int*      deg     = (int*)(ws + carve((size_t)N * 4));
  int*      row_ptr = (int*)(ws + carve((size_t)N * 4));
  float*    dinv    = (float*)(ws + carve((size_t)N * 4));
  int*      bfill   = (int*)(ws + carve((size_t)NB * 4));
  int*      bbase   = (int*)(ws + carve((size_t)NB * 4));
  __half*   wt1     = (__half*)(ws + carve(16384 * 2));
  __half*   wt2     = (__half*)(ws + carve(8192 * 2));
  unsigned* slab    = (unsigned*)(ws + carve((size_t)NB * SLAB * 4));
  int*      ssrc    = (int*)(ws + carve((size_t)E * 4));
  __half*   h1      = (__half*)(ws + carve((size_t)N * K * 2));  // slab layout
  float*    out1    = (float*)(ws + carve((size_t)N * K * 4));
  if (off > ws_size) return;

  __half* h2 = h1;  // h1 dead after agg1 (h2 slab layout [4][N][16])
  float* out2 = (float*)d_out;

  (void)hipMemsetAsync(bfill, 0, (size_t)NB * 4, stream);
  k_prep<<<96, 256, 0, stream>>>(W1, W2, wt1, wt2);
  const int nwg1 = (E + P1_EDGES - 1) / P1_EDGES;
  k_p1<<<nwg1, 256, 0, stream>>>(src, dst, E, NB, bfill, slab);
  k_bscan<<<1, 1024, 0, stream>>>(bfill, NB, bbase);
  k_p2<<<NB, 256, 0, stream>>>(slab, bfill, bbase, N, deg, row_ptr, dinv, ssrc);

  const int bps = (N + 31) / 32;  // blocks per slice (4 waves x 8 nodes)
  k_gemm<128><<<(N + 63) / 64, 256, 0, stream>>>(x, wt1, dinv, h1, N);
  k_aggs<128, 8, true><<<bps * 8, 256, 0, stream>>>(h1, row_ptr, deg, ssrc, dinv,
                                                    b1, out1, N);
  k_gemm<64><<<(N + 63) / 64, 256, 0, stream>>>(out1, wt2, dinv, h2, N);
  k_aggs<64, 4, false><<<bps * 4, 256, 0, stream>>>(h2, row_ptr, deg, ssrc, dinv,
                                                    b2, out2, N);
  (void)n_in; (void)out_size;
}

// Round 8
// 361.170 us; speedup vs baseline: 1.3599x; 1.3599x over previous
//
#include <hip/hip_runtime.h>
#include <hip/hip_fp16.h>

// ---------------------------------------------------------------------------
// 2-layer GCN on MI355X.
// R1: 3-phase scan. R2: h fp16. R3: two-level LDS counting-sort CSR build.
// R5: fp16 MFMA GEMMs (mfma_f32_16x16x32_f16), W pre-transposed.
// R6/R7: XCD-pinned 16-col slices cut FETCH 193->67MB but full-wave-per-node
//     structure serialized (shfl tree + rp/dg latency per node-slice): 266us.
// R8: sliced agg restructured: 2 lanes per edge-row (32B), 32 independent
//     node-groups per wave, per-group sequential edge walk w/ 2-edge unroll,
//     accumulate 8 cols in registers -> NO cross-lane reduce, no shfl.
//     Slice = blockIdx % NSL pins each 3.2MB slab to one XCD's L2.
// ---------------------------------------------------------------------------

typedef _Float16 half8 __attribute__((ext_vector_type(8)));
typedef float f32x4 __attribute__((ext_vector_type(4)));

constexpr int BK_SHIFT = 7;               // 128 nodes per bucket
constexpr int BK_NODES = 1 << BK_SHIFT;
constexpr int NB_MAX   = 1024;
constexpr int SLAB     = 2560;            // mean 2046 + 11 sigma
constexpr int P1_EPT   = 32;
constexpr int P1_EDGES = 256 * P1_EPT;    // 8192

// ---- pass 1: LDS counting sort of 8192 edges into coarse buckets ----
__global__ __launch_bounds__(256) void k_p1(const int* __restrict__ src,
                                            const int* __restrict__ dst, int E,
                                            int NB, int* __restrict__ bfill,
                                            unsigned* __restrict__ slab) {
  __shared__ unsigned stage[P1_EDGES];
  __shared__ unsigned short bidp[P1_EDGES];
  __shared__ int hist[NB_MAX];
  __shared__ int lbase[NB_MAX];
  __shared__ int goff[NB_MAX];
  __shared__ int part[256];

  const int t = threadIdx.x;
  const long base = (long)blockIdx.x * P1_EDGES;
  const int nval = (int)(((long)E - base < (long)P1_EDGES) ? (E - base) : P1_EDGES);

  for (int i = t; i < NB; i += 256) hist[i] = 0;
  __syncthreads();

  int eb[P1_EPT];
  unsigned ev[P1_EPT];
#pragma unroll
  for (int i = 0; i < P1_EPT; ++i) {
    long e = base + t + i * 256;
    int b = -1;
    unsigned v = 0;
    if (e < E) {
      int d = dst[e];
      int s = src[e];
      b = d >> BK_SHIFT;
      v = ((unsigned)(d & (BK_NODES - 1)) << 17) | (unsigned)s;
      atomicAdd(&hist[b], 1);
    }
    eb[i] = b;
    ev[i] = v;
  }
  __syncthreads();

  int lc[4];
  int lsum = 0;
#pragma unroll
  for (int j = 0; j < 4; ++j) {
    int b = t * 4 + j;
    lc[j] = (b < NB) ? hist[b] : 0;
    lsum += lc[j];
  }
  part[t] = lsum;
  __syncthreads();
  for (int o = 1; o < 256; o <<= 1) {
    int a = (t >= o) ? part[t - o] : 0;
    __syncthreads();
    part[t] += a;
    __syncthreads();
  }
  int run = part[t] - lsum;
#pragma unroll
  for (int j = 0; j < 4; ++j) {
    int b = t * 4 + j;
    if (b < NB) lbase[b] = run;
    run += lc[j];
  }
  __syncthreads();

  for (int b = t; b < NB; b += 256) {
    int len = hist[b];
    int g = len ? atomicAdd(&bfill[b], len) : 0;
    goff[b] = b * SLAB + g - lbase[b];
  }
  __syncthreads();

#pragma unroll
  for (int i = 0; i < P1_EPT; ++i) {
    if (eb[i] >= 0) {
      int p = atomicAdd(&lbase[eb[i]], 1);
      stage[p] = ev[i];
      bidp[p] = (unsigned short)eb[i];
    }
  }
  __syncthreads();

  for (int p = t; p < nval; p += 256) {
    int b = bidp[p];
    slab[goff[b] + p] = stage[p];
  }
}

__global__ __launch_bounds__(1024) void k_bscan(const int* __restrict__ bfill, int NB,
                                                int* __restrict__ bbase) {
  __shared__ int sm[1024];
  const int t = threadIdx.x;
  int v = (t < NB) ? bfill[t] : 0;
  sm[t] = v;
  __syncthreads();
  for (int o = 1; o < 1024; o <<= 1) {
    int a = (t >= o) ? sm[t - o] : 0;
    __syncthreads();
    sm[t] += a;
    __syncthreads();
  }
  if (t < NB) bbase[t] = sm[t] - v;
}

__global__ __launch_bounds__(256) void k_p2(const unsigned* __restrict__ slab,
                                            const int* __restrict__ bfill,
                                            const int* __restrict__ bbase, int N,
                                            int* __restrict__ deg,
                                            int* __restrict__ row_ptr,
                                            float* __restrict__ dinv,
                                            int* __restrict__ ssrc) {
  __shared__ int hist[BK_NODES];
  __shared__ int lb[BK_NODES];
  const int b = blockIdx.x;
  const int t = threadIdx.x;
  const int len = bfill[b];
  const int gbase = bbase[b];
  const unsigned* seg = slab + (size_t)b * SLAB;

  if (t < BK_NODES) hist[t] = 0;
  __syncthreads();
  for (int i = t; i < len; i += 256) atomicAdd(&hist[seg[i] >> 17], 1);
  __syncthreads();

  if (t < BK_NODES) lb[t] = hist[t];
  __syncthreads();
  for (int o = 1; o < BK_NODES; o <<= 1) {
    int a = 0;
    if (t < BK_NODES && t >= o) a = lb[t - o];
    __syncthreads();
    if (t < BK_NODES) lb[t] += a;
    __syncthreads();
  }

  int n = b * BK_NODES + t;
  if (t < BK_NODES && n < N) {
    int d = hist[t];
    deg[n] = d;
    row_ptr[n] = gbase + lb[t] - d;
    dinv[n] = rsqrtf((float)(d + 1));
  }
  __syncthreads();
  if (t < BK_NODES) lb[t] -= hist[t];
  __syncthreads();

  for (int i = t; i < len; i += 256) {
    unsigned v = seg[i];
    int l = v >> 17;
    int p = atomicAdd(&lb[l], 1);
    ssrc[gbase + p] = (int)(v & 0x1FFFF);
  }
}

// ---- prep: W (fp32, [K][NC]) -> Wt (fp16, [NC][K]) ----
__global__ __launch_bounds__(256) void k_prep(const float* __restrict__ W1,
                                              const float* __restrict__ W2,
                                              __half* __restrict__ Wt1,
                                              __half* __restrict__ Wt2) {
  int i = blockIdx.x * blockDim.x + threadIdx.x;
  if (i < 16384) {
    int k = i >> 7, n = i & 127;
    Wt1[n * 128 + k] = __float2half(W1[i]);
  } else if (i < 24576) {
    int j = i - 16384;
    int k = j >> 6, n = j & 63;
    Wt2[n * 128 + k] = __float2half(W2[j]);
  }
}

// ---- MFMA GEMM: H_slab[nt][row][lm] = (X @ W)[row][nt*16+lm] * dinv[row].
// Output in column-slab layout: slab nt (16 cols) contiguous [N][16] fp16.
template <int NC>
__global__ __launch_bounds__(256) void k_gemm(const float* __restrict__ X,
                                              const __half* __restrict__ Wt,
                                              const float* __restrict__ dinv,
                                              __half* __restrict__ Hs, int N) {
  constexpr int K = 128;
  constexpr int BM = 64;
  constexpr int LDK = K + 8;
  constexpr int NT = NC / 16;
  __shared__ _Float16 xs[BM * LDK];
  __shared__ _Float16 wl[NC * LDK];

  const int t = threadIdx.x;
  const int r0 = blockIdx.x * BM;

  for (int i = t; i < BM * (K / 4); i += 256) {
    int row = i >> 5, kg = i & 31;
    float4 v = make_float4(0.f, 0.f, 0.f, 0.f);
    if (r0 + row < N)
      v = *reinterpret_cast<const float4*>(X + (size_t)(r0 + row) * K + 4 * kg);
    union { _Float16 h[4]; unsigned long long u; } pk;
    pk.h[0] = (_Float16)v.x; pk.h[1] = (_Float16)v.y;
    pk.h[2] = (_Float16)v.z; pk.h[3] = (_Float16)v.w;
    *reinterpret_cast<unsigned long long*>(&xs[row * LDK + 4 * kg]) = pk.u;
  }
  for (int i = t; i < NC * (K / 8); i += 256) {
    int n = i >> 4, kc = i & 15;
    float4 raw = *reinterpret_cast<const float4*>(Wt + (size_t)n * K + 8 * kc);
    *reinterpret_cast<float4*>(&wl[n * LDK + 8 * kc]) = raw;
  }
  __syncthreads();

  const int w = t >> 6;
  const int lane = t & 63;
  const int lm = lane & 15;
  const int lg = lane >> 4;

  half8 a[4];
#pragma unroll
  for (int kt = 0; kt < 4; ++kt)
    a[kt] = *reinterpret_cast<const half8*>(&xs[(w * 16 + lm) * LDK + kt * 32 + lg * 8]);

  f32x4 acc[NT];
#pragma unroll
  for (int nt = 0; nt < NT; ++nt) acc[nt] = (f32x4){0.f, 0.f, 0.f, 0.f};

#pragma unroll
  for (int nt = 0; nt < NT; ++nt) {
#pragma unroll
    for (int kt = 0; kt < 4; ++kt) {
      half8 b = *reinterpret_cast<const half8*>(
          &wl[(nt * 16 + lm) * LDK + kt * 32 + lg * 8]);
      acc[nt] = __builtin_amdgcn_mfma_f32_16x16x32_f16(a[kt], b, acc[nt], 0, 0, 0);
    }
  }

  float dv[4];
#pragma unroll
  for (int r = 0; r < 4; ++r) {
    int row = r0 + w * 16 + lg * 4 + r;
    dv[r] = (row < N) ? dinv[row] : 0.f;
  }
#pragma unroll
  for (int nt = 0; nt < NT; ++nt) {
#pragma unroll
    for (int r = 0; r < 4; ++r) {
      int row = r0 + w * 16 + lg * 4 + r;
      if (row < N)
        Hs[(size_t)nt * N * 16 + (size_t)row * 16 + lm] =
            __float2half(acc[nt][r] * dv[r]);
    }
  }
}

// ---- XCD-pinned sliced aggregation, group-per-node ----
// Hs: [C/16][N][16] fp16 slabs. slice = blockIdx % NSL -> one XCD (NSL=8) or
// an XCD pair (NSL=4); 3.2MB slab stays L2-resident.
// 2 lanes per edge-row (32B = 2x16B); 32 independent node-groups per wave;
// each group walks its own edge list (2-edge unroll), accumulating its 8
// columns in registers. No cross-lane reduction.
template <int C, int NSL, bool RELU>
__global__ __launch_bounds__(256) void k_aggp(const __half* __restrict__ Hs,
                                              const int* __restrict__ rp,
                                              const int* __restrict__ dg,
                                              const int* __restrict__ ssrc,
                                              const float* __restrict__ dinv,
                                              const float* __restrict__ bias,
                                              float* __restrict__ out, int N) {
  const int slice = blockIdx.x % NSL;
  const int g = blockIdx.x / NSL;
  const int t = threadIdx.x;
  const int hs = t & 1;            // 8-col half of the 16-col slice
  const int n = g * 128 + (t >> 1);
  if (n >= N) return;

  const __half* __restrict__ slabp = Hs + (size_t)slice * N * 16;
  const int e0 = rp[n];
  const int e1 = e0 + dg[n];

  float acc[8];
  {
    half8 v = *reinterpret_cast<const half8*>(slabp + (size_t)n * 16 + hs * 8);
#pragma unroll
    for (int j = 0; j < 8; ++j) acc[j] = (float)v[j];
  }

  int e = e0;
  for (; e + 2 <= e1; e += 2) {
    int s0 = __builtin_nontemporal_load(ssrc + e);
    int s1 = __builtin_nontemporal_load(ssrc + e + 1);
    half8 v0 = *reinterpret_cast<const half8*>(slabp + (size_t)s0 * 16 + hs * 8);
    half8 v1 = *reinterpret_cast<const half8*>(slabp + (size_t)s1 * 16 + hs * 8);
#pragma unroll
    for (int j = 0; j < 8; ++j) acc[j] += (float)v0[j] + (float)v1[j];
  }
  if (e < e1) {
    int s = __builtin_nontemporal_load(ssrc + e);
    half8 v = *reinterpret_cast<const half8*>(slabp + (size_t)s * 16 + hs * 8);
#pragma unroll
    for (int j = 0; j < 8; ++j) acc[j] += (float)v[j];
  }

  const float dv = dinv[n];
  const float* bp = bias + slice * 16 + hs * 8;
  f32x4 o0, o1;
#pragma unroll
  for (int j = 0; j < 4; ++j) {
    o0[j] = acc[j] * dv + bp[j];
    o1[j] = acc[j + 4] * dv + bp[j + 4];
  }
  if (RELU) {
#pragma unroll
    for (int j = 0; j < 4; ++j) {
      o0[j] = fmaxf(o0[j], 0.f);
      o1[j] = fmaxf(o1[j], 0.f);
    }
  }
  float* op = out + (size_t)n * C + slice * 16 + hs * 8;
  __builtin_nontemporal_store(o0, reinterpret_cast<f32x4*>(op));
  __builtin_nontemporal_store(o1, reinterpret_cast<f32x4*>(op + 4));
}

extern "C" void kernel_launch(void* const* d_in, const int* in_sizes, int n_in,
                              void* d_out, int out_size, void* d_ws, size_t ws_size,
                              hipStream_t stream) {
  const float* x = (const float*)d_in[0];
  const int* ei = (const int*)d_in[1];
  const float* W1 = (const float*)d_in[2];
  const float* b1 = (const float*)d_in[3];
  const float* W2 = (const float*)d_in[4];
  const float* b2 = (const float*)d_in[5];

  const int K = 128;
  const int N = in_sizes[0] / K;     // 100000
  const int E = in_sizes[1] / 2;     // 1600000
  const int NB = (N + BK_NODES - 1) >> BK_SHIFT;  // 782
  if (NB > NB_MAX) return;

  const int* src = ei;
  const int* dst = ei + E;

  size_t off = 0;
  auto carve = [&](size_t bytes) {
    size_t o = off;
    off += (bytes + 255) & ~(size_t)255;
    return o;
  };
  char* ws = (char*)d_ws;
  int*      deg     = (int*)(ws + carve((size_t)N * 4));
  int*      row_ptr = (int*)(ws + carve((size_t)N * 4));
  float*    dinv    = (float*)(ws + carve((size_t)N * 4));
  int*      bfill   = (int*)(ws + carve((size_t)NB * 4));
  int*      bbase   = (int*)(ws + carve((size_t)NB * 4));
  __half*   wt1     = (__half*)(ws + carve(16384 * 2));
  __half*   wt2     = (__half*)(ws + carve(8192 * 2));
  unsigned* slab    = (unsigned*)(ws + carve((size_t)NB * SLAB * 4));
  int*      ssrc    = (int*)(ws + carve((size_t)E * 4));
  __half*   h1      = (__half*)(ws + carve((size_t)N * K * 2));  // slab layout
  float*    out1    = (float*)(ws + carve((size_t)N * K * 4));
  if (off > ws_size) return;

  __half* h2 = h1;  // h1 dead after agg1 (h2 slab layout [4][N][16])
  float* out2 = (float*)d_out;

  (void)hipMemsetAsync(bfill, 0, (size_t)NB * 4, stream);
  k_prep<<<96, 256, 0, stream>>>(W1, W2, wt1, wt2);
  const int nwg1 = (E + P1_EDGES - 1) / P1_EDGES;
  k_p1<<<nwg1, 256, 0, stream>>>(src, dst, E, NB, bfill, slab);
  k_bscan<<<1, 1024, 0, stream>>>(bfill, NB, bbase);
  k_p2<<<NB, 256, 0, stream>>>(slab, bfill, bbase, N, deg, row_ptr, dinv, ssrc);

  const int bpg = (N + 127) / 128;  // node-groups of 128 per block
  k_gemm<128><<<(N + 63) / 64, 256, 0, stream>>>(x, wt1, dinv, h1, N);
  k_aggp<128, 8, true><<<bpg * 8, 256, 0, stream>>>(h1, row_ptr, deg, ssrc, dinv,
                                                    b1, out1, N);
  k_gemm<64><<<(N + 63) / 64, 256, 0, stream>>>(out1, wt2, dinv, h2, N);
  k_aggp<64, 4, false><<<bpg * 4, 256, 0, stream>>>(h2, row_ptr, deg, ssrc, dinv,
                                                    b2, out2, N);
  (void)n_in; (void)out_size;
}